// Round 22
// baseline (44.927 us; speedup 1.0000x reference)
//
#include <hip/hip_runtime.h>
#include <hip/hip_fp16.h>
#include <math.h>

// Problem constants (fixed by the harness's setup_inputs)
#define HDIM 256
#define NDIM 64
#define LDIM 8192
#define LF   4097          // L/2 + 1
#define MDIM 4096          // L/2  (complex FFT size = 4^6)
#define LOG2M 12
#define TW4N 3072          // radix-4 twiddles: e^{+2pi i j/4096}, j<3072

typedef _Float16 f16x8 __attribute__((ext_vector_type(8)));
typedef float    f32x4 __attribute__((ext_vector_type(4)));

// round-nearest f32 pair -> packed f16 dword
__device__ __forceinline__ int cvt_pk_f16(float lo, float hi) {
    union { __half2 h; int i; } u;
    u.h = __floats2half2_rn(lo, hi);
    return u.i;
}

// XOR bank swizzle (bijective on low 4 bits; consistent across all accesses)
__device__ __forceinline__ int swz(int i) {
    return i ^ (((i >> 4) ^ (i >> 8)) & 15);
}

// base-4 digit reversal of a 12-bit index
__device__ __forceinline__ int drev(unsigned x) {
    unsigned y = __brev(x) >> (32 - LOG2M);
    return (int)(((y & 0x555u) << 1) | ((y >> 1) & 0x555u));
}

// ---------------------------------------------------------------------------
// R22: SPLIT. The fused design pins 16 waves/CU (256 blocks, 1/CU); the
// cauchy phase is latency-bound at 54% idle. Kernel 1 runs at 2048 blocks
// (8 blocks/CU resident at VGPR<=64 -> 32 waves/CU) with all R19/R20 opts;
// kernel 2 does pack + 6 radix-4 stages. kf round-trips HBM/L2 (~8.4 MB).
// launch_bounds(256,4): cap 128, natural VGPR ~60 -> HW occupancy 8 w/SIMD
// (NOT allocator-forced — avoids the R17 spill trap).
// ---------------------------------------------------------------------------
__global__ __launch_bounds__(256, 4) void cauchy_kernel(
    const float* __restrict__ log_dt,
    const float* __restrict__ C_re, const float* __restrict__ C_im,
    const float* __restrict__ B_re, const float* __restrict__ B_im,
    const float* __restrict__ P_re, const float* __restrict__ P_im,
    const float* __restrict__ Q_re, const float* __restrict__ Q_im,
    const float* __restrict__ w_re, const float* __restrict__ w_im,
    float2* __restrict__ kf)
{
    const int h    = blockIdx.y;
    const int tid  = threadIdx.x;
    const int lane = tid & 63;
    const int wave = tid >> 6;
    const int g    = lane >> 4;     // k-block index (0..3)
    const int m    = lane & 15;     // col (l-offset) and A-row index
    const float dt = expf(log_dt[h]);
    const float dtM = dt * (1.f / (float)MDIM);   // dt/M (E-factor scale)
    const int hb   = h * NDIM;

    // ---- Nyquist bin (l = 4096): k_f = 0.5*(dt/M)*sum_n v00[n] ----
    if (blockIdx.x == 0 && tid < 64) {
        const float br = B_re[hb + lane], bi = B_im[hb + lane];
        const float cr = C_re[hb + lane], ci = C_im[hb + lane];
        float sr = cr * br - ci * bi;
        float si = cr * bi + ci * br;
        #pragma unroll
        for (int off = 32; off > 0; off >>= 1) {
            sr += __shfl_xor(sr, off);
            si += __shfl_xor(si, off);
        }
        if (tid == 0)
            kf[(size_t)h * LF + MDIM] = make_float2(0.5f * dtM * sr, 0.5f * dtM * si);
    }

    // ---- per-lane constants: pole params for this lane's 16 n + A frags ----
    float nwr_[16], nw2_[16], wi_[16];
    int   av[4][4];                 // A fragment dwords (2 f16 each)
    {
        const bool arow = (m < 8);
        const int  ai   = m >> 1;   // 0:C*B 1:C*P 2:Q*B 3:Q*P
        const int  c    = m & 1;    // 0:re-row 1:im-row
        const float* fre = (ai >= 2) ? Q_re : C_re;
        const float* fim = (ai >= 2) ? Q_im : C_im;
        const float* sre = (ai & 1) ? P_re : B_re;
        const float* sim = (ai & 1) ? P_im : B_im;
        #pragma unroll
        for (int q = 0; q < 4; ++q) {
            #pragma unroll
            for (int t = 0; t < 4; ++t) {
                const int n = hb + 16 * q + 4 * g + t;
                const float nw = -w_re[n] * dt;    // > 0
                nwr_[q * 4 + t] = nw;
                nw2_[q * 4 + t] = nw * nw;
                wi_[q * 4 + t]  = w_im[n] * dt;
                float e0 = 0.f, e1 = 0.f;
                if (arow) {
                    const float fr = fre[n], fi = fim[n];
                    const float s2r = sre[n], s2i = sim[n];
                    const float vr = fr * s2r - fi * s2i;
                    const float vi = fr * s2i + fi * s2r;
                    e0 = c ? vi : vr;
                    e1 = c ? vr : -vi;
                }
                av[q][t] = cvt_pk_f16(e0, e1);
            }
        }
    }

    // ---- wave owns l = bx*512 + wave*128 + t8*16 + m, t8 = 0..7 ----
    const int lbase = blockIdx.x * 512 + wave * 128 + m;

    // precompute zt for the 8 tiles (no loop-carried recurrence)
    float zt_[8];
    {
        float ch, sh;
        const float a0 = (3.14159265358979323846f / (float)LDIM) * (float)lbase;
        sincosf(a0, &sh, &ch);
        const float cd = 0.99998117528260114265f;   // cos(pi/512)
        const float sd = 0.00613588464915447536f;   // sin(pi/512)
        #pragma unroll
        for (int t8 = 0; t8 < 8; ++t8) {
            zt_[t8] = 2.f * sh * __builtin_amdgcn_rcpf(ch);  // 2 tan(th/2)
            const float chn = ch * cd - sh * sd;
            const float shn = sh * cd + ch * sd;
            ch = chn; sh = shn;
        }
    }

    #pragma unroll 4
    for (int t8 = 0; t8 < 8; ++t8) {
        const float zt = zt_[t8];

        f32x4 acc0 = {0.f, 0.f, 0.f, 0.f};
        f32x4 acc1 = {0.f, 0.f, 0.f, 0.f};
        #pragma unroll
        for (int q = 0; q < 4; ++q) {
            // B-build with pair-wise rcp: 1 v_rcp per 2 poles
            float den[4], tim[4];
            #pragma unroll
            for (int t = 0; t < 4; ++t) {
                tim[t] = zt - wi_[q * 4 + t];            // Im(z - wdt)
                den[t] = fmaf(tim[t], tim[t], nw2_[q * 4 + t]);
            }
            const float p01 = den[0] * den[1];
            const float p23 = den[2] * den[3];
            const float rp01 = __builtin_amdgcn_rcpf(p01);
            const float rp23 = __builtin_amdgcn_rcpf(p23);
            const float rc0 = rp01 * den[1], rc1 = rp01 * den[0];
            const float rc2 = rp23 * den[3], rc3 = rp23 * den[2];

            int bv[4];
            bv[0] = cvt_pk_f16(nwr_[q * 4 + 0] * rc0, -(tim[0] * rc0));
            bv[1] = cvt_pk_f16(nwr_[q * 4 + 1] * rc1, -(tim[1] * rc1));
            bv[2] = cvt_pk_f16(nwr_[q * 4 + 2] * rc2, -(tim[2] * rc2));
            bv[3] = cvt_pk_f16(nwr_[q * 4 + 3] * rc3, -(tim[3] * rc3));

            union { int i[4]; f16x8 v; } ua, ub;
            ua.i[0] = av[q][0]; ua.i[1] = av[q][1];
            ua.i[2] = av[q][2]; ua.i[3] = av[q][3];
            ub.i[0] = bv[0]; ub.i[1] = bv[1]; ub.i[2] = bv[2]; ub.i[3] = bv[3];
            if (q < 2)
                acc0 = __builtin_amdgcn_mfma_f32_16x16x32_f16(ua.v, ub.v, acc0, 0, 0, 0);
            else
                acc1 = __builtin_amdgcn_mfma_f32_16x16x32_f16(ua.v, ub.v, acc1, 0, 0, 0);
        }
        const f32x4 acc = acc0 + acc1;

        // epilogue: lanes 0-15 hold V00,V01; 16-31 hold V10,V11
        const float o0 = __shfl_xor(acc[0], 16);
        const float o1 = __shfl_xor(acc[1], 16);
        const float o2 = __shfl_xor(acc[2], 16);
        const float o3 = __shfl_xor(acc[3], 16);
        if (lane < 16) {
            const int l = lbase + t8 * 16;
            const float numr = acc[2] * o0 - acc[3] * o1;
            const float numi = acc[2] * o1 + acc[3] * o0;
            const float d_r  = 1.f + dt * o2;
            const float d_i  = dt * o3;
            const float dd   = fmaf(d_r, d_r, d_i * d_i);
            const float rr2  = __builtin_amdgcn_rcpf(dd);
            const float cr = dt * ((numr * d_r + numi * d_i) * rr2);
            const float ci = dt * ((numi * d_r - numr * d_i) * rr2);
            const float Tr = acc[0] - cr;
            const float Ti = acc[1] - ci;
            // E = (dt/M)*(1, zt/2): 1/M folded; FFT-kernel stores are copies
            const float Ei = 0.5f * dtM * zt;
            kf[(size_t)h * LF + l] = make_float2(dtM * Tr - Ei * Ti, dtM * Ti + Ei * Tr);
        }
    }
}

// ---------------------------------------------------------------------------
// Kernel 2: Hermitian pack (digit-reversed) + 6 radix-4 DIT stages + store.
// ---------------------------------------------------------------------------
__global__ __launch_bounds__(1024, 4) void ifft_kernel(
    const float2* __restrict__ kf, float2* __restrict__ out2)
{
    __shared__ float2 S[MDIM];       // 32.8 KB (swizzled)
    __shared__ float2 TW4[TW4N];     // 24.6 KB (swizzled)

    const int h   = blockIdx.x;
    const int tid = threadIdx.x;
    const float2* K = kf + (size_t)h * LF;

    // ---- twiddle table: TW4[j] = e^{+2pi i j/4096}, j in [0,3072) ----
    for (int p = tid; p < TW4N; p += 1024) {
        float s, c;
        sincosf((6.28318530717958647692f / 4096.f) * (float)p, &s, &c);
        TW4[swz(p)] = make_float2(c, s);
    }

    // ---- pack: read kf (global), write digit-reversed Z into S ----
    const int l0 = tid;            // 0..1023
    const int l1 = tid + 1024;     // 1024..2047
    const float2 Kl0 = K[l0];
    const float2 Km0 = K[MDIM - l0];   // l0=0 -> Nyquist cell
    const float2 Kl1 = K[l1];
    const float2 Km1 = K[MDIM - l1];

    // pack twiddles: w0 = e^{+i*pi*l0/4096}; w1 = w0 * e^{+i*pi/4}
    float w0s, w0c;
    sincosf((3.14159265358979323846f / (float)MDIM) * (float)l0, &w0s, &w0c);
    const float r2 = 0.70710678118654752440f;
    const float w1c = (w0c - w0s) * r2;
    const float w1s = (w0s + w0c) * r2;

    __syncthreads();   // TW4 ready (also covers S writes below ordering)

    {
        // l0 slot
        const float Ar = 0.5f * (Kl0.x + Km0.x);
        const float Ai = 0.5f * (Kl0.y - Km0.y);
        const float Br = 0.5f * (Kl0.x - Km0.x);
        const float Bi = 0.5f * (Kl0.y + Km0.y);
        const float Or = w0c * Br - w0s * Bi;
        const float Oi = w0c * Bi + w0s * Br;
        S[swz(drev((unsigned)l0))] = make_float2(Ar - Oi, Ai + Or);
        if (l0 > 0) {
            S[swz(drev((unsigned)(MDIM - l0)))] = make_float2(Ar + Oi, Or - Ai);
        }
    }
    {
        // l1 slot
        const float Ar = 0.5f * (Kl1.x + Km1.x);
        const float Ai = 0.5f * (Kl1.y - Km1.y);
        const float Br = 0.5f * (Kl1.x - Km1.x);
        const float Bi = 0.5f * (Kl1.y + Km1.y);
        const float Or = w1c * Br - w1s * Bi;
        const float Oi = w1c * Bi + w1s * Br;
        S[swz(drev((unsigned)l1))] = make_float2(Ar - Oi, Ai + Or);
        S[swz(drev((unsigned)(MDIM - l1)))] = make_float2(Ar + Oi, Or - Ai);
    }
    if (tid == 0) {
        // l = 2048: w = e^{i*pi/2} = (0,1) -> Z = (K.x, -K.y)
        const float2 K2 = K[2048];
        S[swz(drev(2048u))] = make_float2(K2.x, -K2.y);
    }

    // ---- 6 radix-4 DIT stages (inverse twiddles from TW4) ----
    #pragma unroll
    for (int stage = 0; stage < 6; ++stage) {
        const int q = 1 << (2 * stage);
        __syncthreads();
        const int pos  = tid & (q - 1);
        const int base = ((tid & ~(q - 1)) << 2) | pos;
        const int f    = pos * (1024 >> (2 * stage));   // pos * 4096/(4q)
        const float2 w1 = TW4[swz(f)];
        const float2 w2 = TW4[swz(2 * f)];
        const float2 w3 = TW4[swz(3 * f)];
        const float2 x0 = S[swz(base)];
        const float2 x1 = S[swz(base + q)];
        const float2 x2 = S[swz(base + 2 * q)];
        const float2 x3 = S[swz(base + 3 * q)];
        const float a1r = w1.x * x1.x - w1.y * x1.y;
        const float a1i = w1.x * x1.y + w1.y * x1.x;
        const float a2r = w2.x * x2.x - w2.y * x2.y;
        const float a2i = w2.x * x2.y + w2.y * x2.x;
        const float a3r = w3.x * x3.x - w3.y * x3.y;
        const float a3i = w3.x * x3.y + w3.y * x3.x;
        const float t0r = x0.x + a2r, t0i = x0.y + a2i;
        const float t1r = x0.x - a2r, t1i = x0.y - a2i;
        const float t2r = a1r + a3r,  t2i = a1i + a3i;
        const float t3r = a1r - a3r,  t3i = a1i - a3i;
        S[swz(base)]         = make_float2(t0r + t2r, t0i + t2i);
        S[swz(base + q)]     = make_float2(t1r - t3i, t1i + t3r);
        S[swz(base + 2 * q)] = make_float2(t0r - t2r, t0i - t2i);
        S[swz(base + 3 * q)] = make_float2(t1r + t3i, t1i - t3r);
    }
    __syncthreads();

    // ---- final store: plain copy (1/M folded upstream) ----
    for (int n = tid; n < MDIM; n += 1024) {
        out2[(size_t)h * MDIM + n] = S[swz(n)];
    }
}

extern "C" void kernel_launch(void* const* d_in, const int* in_sizes, int n_in,
                              void* d_out, int out_size, void* d_ws, size_t ws_size,
                              hipStream_t stream)
{
    const float* log_dt = (const float*)d_in[0];
    const float* C_re   = (const float*)d_in[1];
    const float* C_im   = (const float*)d_in[2];
    const float* B_re   = (const float*)d_in[3];
    const float* B_im   = (const float*)d_in[4];
    const float* P_re   = (const float*)d_in[5];
    const float* P_im   = (const float*)d_in[6];
    const float* Q_re   = (const float*)d_in[7];
    const float* Q_im   = (const float*)d_in[8];
    const float* w_re   = (const float*)d_in[9];
    const float* w_im   = (const float*)d_in[10];

    float2* kf   = (float2*)d_ws;        // 256 * 4097 * 8 B = 8.39 MB
    float2* out2 = (float2*)d_out;

    dim3 grid1(8, HDIM);                 // 2048 blocks, 256 thr each
    cauchy_kernel<<<grid1, 256, 0, stream>>>(log_dt, C_re, C_im, B_re, B_im,
                                             P_re, P_im, Q_re, Q_im,
                                             w_re, w_im, kf);

    ifft_kernel<<<HDIM, 1024, 0, stream>>>(kf, out2);
}

// Round 23
// 36.274 us; speedup vs baseline: 1.2385x; 1.2385x over previous
//
#include <hip/hip_runtime.h>
#include <hip/hip_fp16.h>
#include <math.h>

// Problem constants (fixed by the harness's setup_inputs)
#define HDIM 256
#define NDIM 64
#define LDIM 8192
#define LF   4097          // L/2 + 1
#define MDIM 4096          // L/2  (complex FFT size = 4^6)
#define LOG2M 12
#define TW4N 3072          // radix-4 twiddles: e^{+2pi i j/4096}, j<3072

typedef _Float16 f16x8 __attribute__((ext_vector_type(8)));
typedef float    f32x4 __attribute__((ext_vector_type(4)));

// round-nearest f32 pair -> packed f16 dword
__device__ __forceinline__ int cvt_pk_f16(float lo, float hi) {
    union { __half2 h; int i; } u;
    u.h = __floats2half2_rn(lo, hi);
    return u.i;
}

// XOR bank swizzle (bijective on low 4 bits; consistent across all accesses)
__device__ __forceinline__ int swz(int i) {
    return i ^ (((i >> 4) ^ (i >> 8)) & 15);
}

// base-4 digit reversal of a 12-bit index: bit-reverse, then swap adjacent
// bits to restore intra-digit order.
__device__ __forceinline__ int drev(unsigned x) {
    unsigned y = __brev(x) >> (32 - LOG2M);
    return (int)(((y & 0x555u) << 1) | ((y >> 1) & 0x555u));
}

// ---------------------------------------------------------------------------
// R23 = revert to R21 (best verified: 36.3 us clean, absmax 1.56e-2).
// R22's split falsified the occupancy theory (same 43 us at 2048 blocks);
// this fused design is the declared structural floor:
//   Phase 1 (cauchy, MFMA f16): G = 1/(i*zt - wdt) via z-substitution,
//     V_ab = sum_n v_ab G as K=128 re/im-packed mfma_f32_16x16x32_f16;
//     zt precomputed (no loop-carried recurrence), pair-wise rcp,
//     RN f16 packs, dt/M folded into epilogue E-factor.
//   Phase 2 (irfft): Hermitian pack (digit-reversed) + 6 radix-4 DIT
//     stages in swizzled LDS + coalesced store. kf never touches HBM.
// ---------------------------------------------------------------------------
__global__ __launch_bounds__(1024, 4) void fused_kernel(
    const float* __restrict__ log_dt,
    const float* __restrict__ C_re, const float* __restrict__ C_im,
    const float* __restrict__ B_re, const float* __restrict__ B_im,
    const float* __restrict__ P_re, const float* __restrict__ P_im,
    const float* __restrict__ Q_re, const float* __restrict__ Q_im,
    const float* __restrict__ w_re, const float* __restrict__ w_im,
    float2* __restrict__ out2)
{
    __shared__ float2 S[MDIM + 1];   // 32.8 KB (kf and Z share it; swizzled)
    __shared__ float2 TW4[TW4N];     // 24.6 KB (swizzled)

    const int h    = blockIdx.x;
    const int tid  = threadIdx.x;
    const int lane = tid & 63;
    const int wave = tid >> 6;
    const int g    = lane >> 4;     // k-block index (0..3)
    const int m    = lane & 15;     // col (l-offset) and A-row index
    const float dt = expf(log_dt[h]);
    const float dtM = dt * (1.f / (float)MDIM);   // dt/M (E-factor scale)
    const int hb   = h * NDIM;

    // ---- twiddle table: TW4[j] = e^{+2pi i j/4096}, j in [0,3072) ----
    for (int p = tid; p < TW4N; p += 1024) {
        float s, c;
        sincosf((6.28318530717958647692f / 4096.f) * (float)p, &s, &c);
        TW4[swz(p)] = make_float2(c, s);
    }

    // ---- Nyquist bin (l = 4096): k_f = 0.5*(dt/M)*sum_n v00[n] ----
    if (tid < 64) {
        const float br = B_re[hb + lane], bi = B_im[hb + lane];
        const float cr = C_re[hb + lane], ci = C_im[hb + lane];
        float sr = cr * br - ci * bi;
        float si = cr * bi + ci * br;
        #pragma unroll
        for (int off = 32; off > 0; off >>= 1) {
            sr += __shfl_xor(sr, off);
            si += __shfl_xor(si, off);
        }
        if (tid == 0)
            S[swz(MDIM)] = make_float2(0.5f * dtM * sr, 0.5f * dtM * si);
    }

    // ---- per-lane constants: pole params for this lane's 16 n + A frags ----
    float nwr_[16], nw2_[16], wi_[16];
    int   av[4][4];                 // A fragment dwords (2 f16 each)
    {
        const bool arow = (m < 8);
        const int  ai   = m >> 1;   // 0:C*B 1:C*P 2:Q*B 3:Q*P
        const int  c    = m & 1;    // 0:re-row 1:im-row
        const float* fre = (ai >= 2) ? Q_re : C_re;
        const float* fim = (ai >= 2) ? Q_im : C_im;
        const float* sre = (ai & 1) ? P_re : B_re;
        const float* sim = (ai & 1) ? P_im : B_im;
        #pragma unroll
        for (int q = 0; q < 4; ++q) {
            #pragma unroll
            for (int t = 0; t < 4; ++t) {
                const int n = hb + 16 * q + 4 * g + t;
                const float nw = -w_re[n] * dt;    // > 0
                nwr_[q * 4 + t] = nw;
                nw2_[q * 4 + t] = nw * nw;
                wi_[q * 4 + t]  = w_im[n] * dt;
                float e0 = 0.f, e1 = 0.f;
                if (arow) {
                    const float fr = fre[n], fi = fim[n];
                    const float s2r = sre[n], s2i = sim[n];
                    const float vr = fr * s2r - fi * s2i;
                    const float vi = fr * s2i + fi * s2r;
                    e0 = c ? vi : vr;
                    e1 = c ? vr : -vi;
                }
                av[q][t] = cvt_pk_f16(e0, e1);
            }
        }
    }

    // ---- cauchy phase: wave owns l = wave*256 + t*16 + m, t = 0..15 ----
    const int lbase = wave * 256 + m;

    // precompute zt for all 16 tiles (no loop-carried recurrence)
    float zt_[16];
    {
        float ch, sh;
        const float a0 = (3.14159265358979323846f / (float)LDIM) * (float)lbase;
        sincosf(a0, &sh, &ch);
        const float cd = 0.99998117528260114265f;   // cos(pi/512)
        const float sd = 0.00613588464915447536f;   // sin(pi/512)
        #pragma unroll
        for (int t16 = 0; t16 < 16; ++t16) {
            zt_[t16] = 2.f * sh * __builtin_amdgcn_rcpf(ch);  // 2 tan(th/2)
            const float chn = ch * cd - sh * sd;
            const float shn = sh * cd + ch * sd;
            ch = chn; sh = shn;
        }
    }

    #pragma unroll 4
    for (int t16 = 0; t16 < 16; ++t16) {
        const float zt = zt_[t16];

        f32x4 acc0 = {0.f, 0.f, 0.f, 0.f};
        f32x4 acc1 = {0.f, 0.f, 0.f, 0.f};
        #pragma unroll
        for (int q = 0; q < 4; ++q) {
            // B-build with pair-wise rcp: 1 v_rcp per 2 poles
            float den[4], tim[4];
            #pragma unroll
            for (int t = 0; t < 4; ++t) {
                tim[t] = zt - wi_[q * 4 + t];            // Im(z - wdt)
                den[t] = fmaf(tim[t], tim[t], nw2_[q * 4 + t]);
            }
            const float p01 = den[0] * den[1];
            const float p23 = den[2] * den[3];
            const float rp01 = __builtin_amdgcn_rcpf(p01);
            const float rp23 = __builtin_amdgcn_rcpf(p23);
            const float rc0 = rp01 * den[1], rc1 = rp01 * den[0];
            const float rc2 = rp23 * den[3], rc3 = rp23 * den[2];

            int bv[4];
            bv[0] = cvt_pk_f16(nwr_[q * 4 + 0] * rc0, -(tim[0] * rc0));
            bv[1] = cvt_pk_f16(nwr_[q * 4 + 1] * rc1, -(tim[1] * rc1));
            bv[2] = cvt_pk_f16(nwr_[q * 4 + 2] * rc2, -(tim[2] * rc2));
            bv[3] = cvt_pk_f16(nwr_[q * 4 + 3] * rc3, -(tim[3] * rc3));

            union { int i[4]; f16x8 v; } ua, ub;
            ua.i[0] = av[q][0]; ua.i[1] = av[q][1];
            ua.i[2] = av[q][2]; ua.i[3] = av[q][3];
            ub.i[0] = bv[0]; ub.i[1] = bv[1]; ub.i[2] = bv[2]; ub.i[3] = bv[3];
            if (q < 2)
                acc0 = __builtin_amdgcn_mfma_f32_16x16x32_f16(ua.v, ub.v, acc0, 0, 0, 0);
            else
                acc1 = __builtin_amdgcn_mfma_f32_16x16x32_f16(ua.v, ub.v, acc1, 0, 0, 0);
        }
        const f32x4 acc = acc0 + acc1;

        // epilogue: lanes 0-15 hold V00,V01; 16-31 hold V10,V11
        const float o0 = __shfl_xor(acc[0], 16);
        const float o1 = __shfl_xor(acc[1], 16);
        const float o2 = __shfl_xor(acc[2], 16);
        const float o3 = __shfl_xor(acc[3], 16);
        if (lane < 16) {
            const int l = lbase + t16 * 16;
            const float numr = acc[2] * o0 - acc[3] * o1;
            const float numi = acc[2] * o1 + acc[3] * o0;
            const float d_r  = 1.f + dt * o2;
            const float d_i  = dt * o3;
            const float dd   = fmaf(d_r, d_r, d_i * d_i);
            const float rr2  = __builtin_amdgcn_rcpf(dd);
            const float cr = dt * ((numr * d_r + numi * d_i) * rr2);
            const float ci = dt * ((numi * d_r - numr * d_i) * rr2);
            const float Tr = acc[0] - cr;
            const float Ti = acc[1] - ci;
            // E = (dt/M) * (1, zt/2)  — 1/M folded, final store is a copy
            const float Ei = 0.5f * dtM * zt;
            S[swz(l)] = make_float2(dtM * Tr - Ei * Ti, dtM * Ti + Ei * Tr);
        }
    }

    __syncthreads();

    // ---- pack phase (aliased): read kf values to registers ----
    const int l0 = tid;            // 0..1023
    const int l1 = tid + 1024;     // 1024..2047
    const float2 Kl0 = S[swz(l0)];
    const float2 Km0 = S[swz(MDIM - l0)];   // l0=0 -> Nyquist cell
    const float2 Kl1 = S[swz(l1)];
    const float2 Km1 = S[swz(MDIM - l1)];
    float2 K2;
    if (tid == 0) K2 = S[swz(2048)];

    // pack twiddles: w0 = e^{+i*pi*l0/4096}; w1 = w0 * e^{+i*pi/4}
    float w0s, w0c;
    sincosf((3.14159265358979323846f / (float)MDIM) * (float)l0, &w0s, &w0c);
    const float r2 = 0.70710678118654752440f;
    const float w1c = (w0c - w0s) * r2;
    const float w1s = (w0s + w0c) * r2;

    __syncthreads();

    // ---- write digit-reversed Z into S (in place) ----
    {
        // l0 slot
        const float Ar = 0.5f * (Kl0.x + Km0.x);
        const float Ai = 0.5f * (Kl0.y - Km0.y);
        const float Br = 0.5f * (Kl0.x - Km0.x);
        const float Bi = 0.5f * (Kl0.y + Km0.y);
        const float Or = w0c * Br - w0s * Bi;
        const float Oi = w0c * Bi + w0s * Br;
        S[swz(drev((unsigned)l0))] = make_float2(Ar - Oi, Ai + Or);
        if (l0 > 0) {
            S[swz(drev((unsigned)(MDIM - l0)))] = make_float2(Ar + Oi, Or - Ai);
        }
    }
    {
        // l1 slot
        const float Ar = 0.5f * (Kl1.x + Km1.x);
        const float Ai = 0.5f * (Kl1.y - Km1.y);
        const float Br = 0.5f * (Kl1.x - Km1.x);
        const float Bi = 0.5f * (Kl1.y + Km1.y);
        const float Or = w1c * Br - w1s * Bi;
        const float Oi = w1c * Bi + w1s * Br;
        S[swz(drev((unsigned)l1))] = make_float2(Ar - Oi, Ai + Or);
        S[swz(drev((unsigned)(MDIM - l1)))] = make_float2(Ar + Oi, Or - Ai);
    }
    if (tid == 0) {
        // l = 2048: w = e^{i*pi/2} = (0,1) -> Z = (K.x, -K.y)
        S[swz(drev(2048u))] = make_float2(K2.x, -K2.y);
    }

    // ---- 6 radix-4 DIT stages (inverse twiddles from TW4) ----
    #pragma unroll
    for (int stage = 0; stage < 6; ++stage) {
        const int q = 1 << (2 * stage);
        __syncthreads();
        const int pos  = tid & (q - 1);
        const int base = ((tid & ~(q - 1)) << 2) | pos;
        const int f    = pos * (1024 >> (2 * stage));   // pos * 4096/(4q)
        const float2 w1 = TW4[swz(f)];
        const float2 w2 = TW4[swz(2 * f)];
        const float2 w3 = TW4[swz(3 * f)];
        const float2 x0 = S[swz(base)];
        const float2 x1 = S[swz(base + q)];
        const float2 x2 = S[swz(base + 2 * q)];
        const float2 x3 = S[swz(base + 3 * q)];
        // apply twiddles to x1, x2, x3
        const float a1r = w1.x * x1.x - w1.y * x1.y;
        const float a1i = w1.x * x1.y + w1.y * x1.x;
        const float a2r = w2.x * x2.x - w2.y * x2.y;
        const float a2i = w2.x * x2.y + w2.y * x2.x;
        const float a3r = w3.x * x3.x - w3.y * x3.y;
        const float a3i = w3.x * x3.y + w3.y * x3.x;
        // combine (inverse: y1 = t1 + i*t3, y3 = t1 - i*t3)
        const float t0r = x0.x + a2r, t0i = x0.y + a2i;
        const float t1r = x0.x - a2r, t1i = x0.y - a2i;
        const float t2r = a1r + a3r,  t2i = a1i + a3i;
        const float t3r = a1r - a3r,  t3i = a1i - a3i;
        S[swz(base)]         = make_float2(t0r + t2r, t0i + t2i);
        S[swz(base + q)]     = make_float2(t1r - t3i, t1i + t3r);
        S[swz(base + 2 * q)] = make_float2(t0r - t2r, t0i - t2i);
        S[swz(base + 3 * q)] = make_float2(t1r + t3i, t1i - t3r);
    }
    __syncthreads();

    // ---- final store: plain copy (1/M already folded into E) ----
    for (int n = tid; n < MDIM; n += 1024) {
        out2[(size_t)h * MDIM + n] = S[swz(n)];
    }
}

extern "C" void kernel_launch(void* const* d_in, const int* in_sizes, int n_in,
                              void* d_out, int out_size, void* d_ws, size_t ws_size,
                              hipStream_t stream)
{
    const float* log_dt = (const float*)d_in[0];
    const float* C_re   = (const float*)d_in[1];
    const float* C_im   = (const float*)d_in[2];
    const float* B_re   = (const float*)d_in[3];
    const float* B_im   = (const float*)d_in[4];
    const float* P_re   = (const float*)d_in[5];
    const float* P_im   = (const float*)d_in[6];
    const float* Q_re   = (const float*)d_in[7];
    const float* Q_im   = (const float*)d_in[8];
    const float* w_re   = (const float*)d_in[9];
    const float* w_im   = (const float*)d_in[10];

    float2* out2 = (float2*)d_out;

    fused_kernel<<<HDIM, 1024, 0, stream>>>(log_dt, C_re, C_im, B_re, B_im,
                                            P_re, P_im, Q_re, Q_im,
                                            w_re, w_im, out2);
}